// Round 17
// baseline (138.922 us; speedup 1.0000x reference)
//
#include <hip/hip_runtime.h>

// GraphSAGE 2-layer + global mean pool.
// N=100000 nodes, E=1e6 edges, 64 -> 64 (relu) -> 128 channels, 128 graphs.
// Pipeline: {prep + bcur-init fused} -> binA (fixed-capacity bucket staging)
// -> binB (per-bucket row sort -> padded CSR + rowptr) -> sage conv1/conv2
// (two-pass gather over SPLIT fp8 planes [3.2MB each = L2-resident] + MFMA;
// conv2 fuses register mean-pool) -> finalize(+cnt).

#define IN_CH       64
#define OUT_CH      128
#define N_GRAPHS    128
#define NBUCK_SHIFT 9
#define BROWS       512      // rows per coarse bucket
#define CAPB        8192     // fixed staged/csr capacity per bucket (mean 5120)

typedef __attribute__((ext_vector_type(8))) short bf16x8;   // 8 bf16 = 4 VGPR
typedef __attribute__((ext_vector_type(4))) float f32x4;
typedef __attribute__((ext_vector_type(2))) float f32x2;

#if defined(__has_builtin)
#  if __has_builtin(__builtin_amdgcn_cvt_pk_f32_fp8) && __has_builtin(__builtin_amdgcn_cvt_pk_fp8_f32)
#    define HAS_HW_FP8 1
#  endif
#endif
#ifndef HAS_HW_FP8
#  define HAS_HW_FP8 0
#endif

__device__ __forceinline__ unsigned short f2b(float f) {    // RNE float->bf16
    unsigned int u = __float_as_uint(f);
    return (unsigned short)((u + 0x7FFFu + ((u >> 16) & 1u)) >> 16);
}

#if !HAS_HW_FP8
__device__ __forceinline__ unsigned fp8_enc(float f) {      // e4m3fn RNE
    unsigned u = __float_as_uint(f);
    unsigned s = (u >> 24) & 0x80u;
    float a = fabsf(f);
    if (a >= 448.f) return s | 0x7Eu;
    if (a < 0.015625f) { int m = (int)rintf(a * 512.f); return s | (unsigned)m; }
    unsigned au = __float_as_uint(a);
    au += 0x7FFFFu + ((au >> 20) & 1u);
    if ((au >> 23) > 135u) return s | 0x7Eu;
    return s | (((au >> 20) & 0x7FFu) - (120u << 3));
}
__device__ __forceinline__ float fp8_dec1(unsigned b) {
    unsigned s = (b & 0x80u) << 24, m = b & 0x7Fu;
    if (m >= 0x08u) return __uint_as_float(s | ((m << 20) + (120u << 23)));
    float v = (float)m * 0.001953125f;
    return __uint_as_float(__float_as_uint(v) | s);
}
#endif

template <bool HI>
__device__ __forceinline__ f32x2 fp8x2_dec(unsigned u) {
#if HAS_HW_FP8
    return __builtin_amdgcn_cvt_pk_f32_fp8((int)u, HI);     // HI immediate
#else
    f32x2 r;
    unsigned b0 = HI ? ((u >> 16) & 0xFFu) : (u & 0xFFu);
    unsigned b1 = HI ? (u >> 24) : ((u >> 8) & 0xFFu);
    r.x = fp8_dec1(b0); r.y = fp8_dec1(b1);
    return r;
#endif
}

__device__ __forceinline__ unsigned fp8x4_enc(float a, float b, float c, float d) {
#if HAS_HW_FP8
    int p = __builtin_amdgcn_cvt_pk_fp8_f32(a, b, 0, false);
    p = __builtin_amdgcn_cvt_pk_fp8_f32(c, d, p, true);
    return (unsigned)p;
#else
    return fp8_enc(a) | (fp8_enc(b) << 8) | (fp8_enc(c) << 16) | (fp8_enc(d) << 24);
#endif
}

__device__ __forceinline__ unsigned char f2fp8(float v) {
#if HAS_HW_FP8
    return (unsigned char)(__builtin_amdgcn_cvt_pk_fp8_f32(v, v, 0, false) & 0xFF);
#else
    return (unsigned char)fp8_enc(v);
#endif
}

// pack 8 consecutive f32 (LDS) * inv -> bf16x8
__device__ __forceinline__ bf16x8 pack8(const float* p, float inv) {
    union { bf16x8 v; unsigned int u[4]; } r;
#pragma unroll
    for (int i = 0; i < 4; i++) {
        unsigned int lo = f2b(p[2 * i] * inv);
        unsigned int hi = f2b(p[2 * i + 1] * inv);
        r.u[i] = (hi << 16) | lo;
    }
    return r.v;
}

// ---------------- prep (+ bcur init in last block) ----------------
// x -> bf16 table + TWO fp8 planes (features 0..31 / 32..63), packed weights.
__global__ __launch_bounds__(256) void prep_kernel(const float* __restrict__ x,
                                                   const float* __restrict__ Wl1,
                                                   const float* __restrict__ Wr1,
                                                   const float* __restrict__ Wl2,
                                                   const float* __restrict__ Wr2,
                                                   unsigned short* __restrict__ xb16,
                                                   unsigned char* __restrict__ xb8a,
                                                   unsigned char* __restrict__ xb8b,
                                                   unsigned short* __restrict__ wc1,
                                                   unsigned short* __restrict__ wc2,
                                                   int* __restrict__ bcur,
                                                   int n4, int nbuck) {
    if ((int)blockIdx.x == (int)gridDim.x - 1) {
        if ((int)threadIdx.x < nbuck) bcur[threadIdx.x] = threadIdx.x * CAPB;
        return;
    }
    int i = blockIdx.x * 256 + threadIdx.x;
    if (i < n4) {
        float4 v = ((const float4*)x)[i];
        ushort4 o;
        o.x = f2b(v.x); o.y = f2b(v.y); o.z = f2b(v.z); o.w = f2b(v.w);
        ((ushort4*)xb16)[i] = o;
        int n = i >> 4, q16 = i & 15;          // features q16*4..q16*4+3
        unsigned pk = fp8x4_enc(v.x, v.y, v.z, v.w);
        if (q16 < 8) ((unsigned*)xb8a)[n * 8 + q16] = pk;
        else         ((unsigned*)xb8b)[n * 8 + (q16 - 8)] = pk;
    } else {
        int j = i - n4;
        if (j < 64 * 128) {
            int oc = j >> 7, k = j & 127;
            float v = (k < 64) ? Wl1[oc * 64 + k] : Wr1[oc * 64 + k - 64];
            wc1[j] = f2b(v);
        } else if (j < 64 * 128 + 128 * 128) {
            int jj = j - 64 * 128;
            int oc = jj >> 7, k = jj & 127;
            float v = (k < 64) ? Wl2[oc * 64 + k] : Wr2[oc * 64 + k - 64];
            wc2[jj] = f2b(v);
        }
    }
}

// ---------------- binA: bin edges into fixed-capacity buckets ----------------
// packed staged value: (local_row<<17) | src   (src < 2^17, local_row < 512)
__global__ __launch_bounds__(256) void binA_kernel(const int* __restrict__ src,
                                                   const int* __restrict__ dst,
                                                   int* __restrict__ bcur,
                                                   int* __restrict__ staged, int E) {
    constexpr int CH = 4096;
    __shared__ int cnt[256];
    __shared__ int cur[256];
    __shared__ int gbase[256];
    __shared__ int lstart[256];
    __shared__ int tmp[256];
    __shared__ int sortedv[CH];
    __shared__ unsigned char sortedb[CH];

    const int tid = threadIdx.x;
    const int e0 = blockIdx.x * CH;
    const int n = min(CH, E - e0);

    cnt[tid] = 0;
    __syncthreads();
    for (int i = tid; i < n; i += 256)
        atomicAdd(&cnt[dst[e0 + i] >> NBUCK_SHIFT], 1);
    __syncthreads();
    int v = cnt[tid];
    int inc = v;
    tmp[tid] = inc;
    __syncthreads();
    for (int o = 1; o < 256; o <<= 1) {
        int t = (tid >= o) ? tmp[tid - o] : 0;
        __syncthreads();
        inc += t;
        tmp[tid] = inc;
        __syncthreads();
    }
    lstart[tid] = inc - v;
    cur[tid] = inc - v;
    if (v > 0) gbase[tid] = atomicAdd(&bcur[tid], v);
    __syncthreads();
    for (int i = tid; i < n; i += 256) {
        int d = dst[e0 + i], s = src[e0 + i];
        int b = d >> NBUCK_SHIFT;
        int p = atomicAdd(&cur[b], 1);
        sortedv[p] = ((d & (BROWS - 1)) << 17) | s;
        sortedb[p] = (unsigned char)b;
    }
    __syncthreads();
    for (int i = tid; i < n; i += 256) {
        int b = sortedb[i];
        staged[gbase[b] + (i - lstart[b])] = sortedv[i];
    }
}

// ---------------- binB: per-bucket row sort -> padded CSR + rowptr ----------------
__global__ __launch_bounds__(256) void binB_kernel(const int* __restrict__ staged,
                                                   const int* __restrict__ bcur,
                                                   int* __restrict__ csr,
                                                   int* __restrict__ rowptr) {
    __shared__ int cnt[BROWS];
    __shared__ int cur[BROWS];
    __shared__ int tmp[BROWS];
    __shared__ int sorted[CAPB];

    const int tid = threadIdx.x;
    const int b = blockIdx.x;
    const int r0 = b * BROWS;
    const int base = b * CAPB;
    const int n = bcur[b] - base;

    for (int k = tid; k < BROWS; k += 256) cnt[k] = 0;
    __syncthreads();
    for (int i = tid; i < n; i += 256)
        atomicAdd(&cnt[staged[base + i] >> 17], 1);
    __syncthreads();
    tmp[tid] = cnt[tid];
    tmp[tid + 256] = cnt[tid + 256];
    __syncthreads();
    for (int o = 1; o < BROWS; o <<= 1) {
        int t0 = (tid >= o) ? tmp[tid - o] : 0;
        int t1 = (tid + 256 >= o) ? tmp[tid + 256 - o] : 0;
        __syncthreads();
        tmp[tid] += t0;
        tmp[tid + 256] += t1;
        __syncthreads();
    }
    cur[tid] = tmp[tid] - cnt[tid];
    cur[tid + 256] = tmp[tid + 256] - cnt[tid + 256];
    rowptr[r0 + tid] = base + cur[tid];               // all rows, incl. empty
    rowptr[r0 + tid + 256] = base + cur[tid + 256];
    __syncthreads();
    for (int i = tid; i < n; i += 256) {
        int p = staged[base + i];
        int pos = atomicAdd(&cur[p >> 17], 1);
        if (pos < CAPB) sorted[pos] = p & 0x1FFFF;
    }
    __syncthreads();
    for (int i = tid; i < n; i += 256)
        csr[base + i] = sorted[min(i, CAPB - 1)];
}

// ---------------- fused SAGE conv ----------------
// Block = 64 dst nodes, 8 blocks/CU. 64 slots (4 waves x 16, 4 lanes each);
// slot owns ONE row. Gather runs TWO PASSES, one per 3.2MB fp8 plane
// (L2-resident working set); per pass a lane loads uint2 = 8 fp8 feats, the
// slot's 4 lanes fetch the 32B half-row; 4-deep pipeline, csr 8-ahead;
// out-of-range prefetches use row 0. MFMA: K=128 (k<64 neighbor-mean tile,
// k>=64 bf16 self), B from global. POOL: register shfl-reduce mean-pool.
template <int OUTC, bool RELU, bool POOL>
__global__ __launch_bounds__(256, 8) void sage_kernel(
    const unsigned char* __restrict__ f8a,      // [N,32] fp8 plane (feat 0..31)
    const unsigned char* __restrict__ f8b,      // [N,32] fp8 plane (feat 32..63)
    const unsigned short* __restrict__ f16,     // [N,64] bf16 (self)
    const int* __restrict__ csr,                // padded CSR (src only)
    const int* __restrict__ rowptr,             // padded coords
    const int* __restrict__ bcur,               // bucket ends
    const unsigned short* __restrict__ wc,      // [OUTC,128] bf16
    const float* __restrict__ bias,             // [OUTC] f32
    unsigned short* __restrict__ out16,         // bf16 [N,OUTC] (POOL=false)
    unsigned char* __restrict__ out8a,          // fp8 plane [N,OUTC/2]
    unsigned char* __restrict__ out8b,          // fp8 plane [N,OUTC/2]
    const int* __restrict__ batch,              // [N] (POOL)
    float* __restrict__ pooled,                 // [G,OUTC] f32 (POOL)
    int N) {
    constexpr int LDA = 68;
    __shared__ float agg[64 * LDA];             // 17.4 KB
    __shared__ int rp[65];
    __shared__ int bt[64];

    const int tid = threadIdx.x, lane = tid & 63, w = tid >> 6;
    const int base = blockIdx.x * 64;

    for (int i = tid; i < 64 * LDA; i += 256) agg[i] = 0.f;
    if (tid < 64) rp[tid] = rowptr[base + tid];
    if (tid == 64) {
        int idx = base + 64;
        rp[64] = ((idx & (BROWS - 1)) == 0) ? bcur[(idx >> NBUCK_SHIFT) - 1]
                                            : rowptr[idx];
    }
    if (POOL && tid < 64) bt[tid] = batch[min(base + tid, N - 1)];
    __syncthreads();

    // ---- gather: 4-lane slot owns one row; 2 plane-passes x 4-deep pipeline ----
    {
        const int sl = (w << 4) | (lane >> 2); // slot 0..63 = local row
        const int fl = lane & 3;               // 8-feature group within plane
        const int e0 = rp[sl];
        const int end = rp[sl + 1];
        if (e0 < end) {
#define CIDX(EI) (((EI) < end) ? csr[EI] : 0)
#pragma unroll 1
            for (int q = 0; q < 2; q++) {
                const uint2* pf = reinterpret_cast<const uint2*>(q ? f8b : f8a);
                float a0 = 0.f, a1 = 0.f, a2 = 0.f, a3 = 0.f;
                float a4 = 0.f, a5 = 0.f, a6 = 0.f, a7 = 0.f;
                int c4_ = CIDX(e0 + 4), c5_ = CIDX(e0 + 5);
                int c6_ = CIDX(e0 + 6), c7_ = CIDX(e0 + 7);
                uint2 v0 = pf[(size_t)CIDX(e0 + 0) * 4 + fl];
                uint2 v1 = pf[(size_t)CIDX(e0 + 1) * 4 + fl];
                uint2 v2 = pf[(size_t)CIDX(e0 + 2) * 4 + fl];
                uint2 v3 = pf[(size_t)CIDX(e0 + 3) * 4 + fl];

#define PROC(VV, EI)                                                             \
    do {                                                                         \
        if ((EI) < end) {                                                        \
            f32x2 d;                                                             \
            d = fp8x2_dec<false>(VV.x); a0 += d.x; a1 += d.y;                    \
            d = fp8x2_dec<true >(VV.x); a2 += d.x; a3 += d.y;                    \
            d = fp8x2_dec<false>(VV.y); a4 += d.x; a5 += d.y;                    \
            d = fp8x2_dec<true >(VV.y); a6 += d.x; a7 += d.y;                    \
        }                                                                        \
    } while (0)

                for (int e = e0; e < end; e += 4) {
                    PROC(v0, e + 0);
                    v0 = pf[(size_t)c4_ * 4 + fl];
                    PROC(v1, e + 1);
                    v1 = pf[(size_t)c5_ * 4 + fl];
                    PROC(v2, e + 2);
                    v2 = pf[(size_t)c6_ * 4 + fl];
                    PROC(v3, e + 3);
                    v3 = pf[(size_t)c7_ * 4 + fl];
                    c4_ = CIDX(e + 8);
                    c5_ = CIDX(e + 9);
                    c6_ = CIDX(e + 10);
                    c7_ = CIDX(e + 11);
                }
                float* dp = &agg[sl * LDA + q * 32 + fl * 8];
                *reinterpret_cast<float4*>(dp + 0) = make_float4(a0, a1, a2, a3);
                *reinterpret_cast<float4*>(dp + 4) = make_float4(a4, a5, a6, a7);
#undef PROC
            }
#undef CIDX
        }
    }
    __syncthreads();

    // ---- MFMA phase ----
    const int hl = lane & 15, sgq = lane >> 4;
    const int row = w * 16 + hl;
    float inv = 1.0f / fmaxf((float)(rp[row + 1] - rp[row]), 1.0f);
    const float* ar = &agg[row * LDA];
    bf16x8 a[4];
    a[0] = pack8(ar + sgq * 8, inv);
    a[1] = pack8(ar + 32 + sgq * 8, inv);
    int nclamp = min(base + row, N - 1);
    const unsigned short* srow = &f16[(size_t)nclamp * 64];
    a[2] = *reinterpret_cast<const bf16x8*>(&srow[sgq * 8]);
    a[3] = *reinterpret_cast<const bf16x8*>(&srow[32 + sgq * 8]);

    int gw0 = 0, gw1 = -1;
    int myg[4];
    bool mval[4];
    if (POOL) {
        gw0 = bt[w * 16];
        gw1 = bt[w * 16 + 15];
#pragma unroll
        for (int r = 0; r < 4; r++) {
            int lrow = w * 16 + sgq * 4 + r;
            mval[r] = (base + lrow) < N;
            myg[r] = bt[lrow];
        }
    }

    constexpr int NT = OUTC / 16;
#pragma unroll
    for (int nt = 0; nt < NT; nt++) {
        f32x4 acc = {0.f, 0.f, 0.f, 0.f};
#pragma unroll
        for (int ks = 0; ks < 4; ks++) {
            bf16x8 b = *reinterpret_cast<const bf16x8*>(
                &wc[(nt * 16 + hl) * 128 + ks * 32 + sgq * 8]);
            acc = __builtin_amdgcn_mfma_f32_16x16x32_bf16(a[ks], b, acc, 0, 0, 0);
        }
        float bv = bias[nt * 16 + hl];
        if (POOL) {
            for (int g = gw0; g <= gw1; g++) {
                float s = 0.f;
#pragma unroll
                for (int r = 0; r < 4; r++) {
                    float v = acc[r] + bv;
                    if (RELU) v = fmaxf(v, 0.f);
                    s += (mval[r] && myg[r] == g) ? v : 0.f;
                }
                s += __shfl_xor(s, 16);
                s += __shfl_xor(s, 32);
                if (lane < 16) atomicAdd(&pooled[g * OUTC + nt * 16 + lane], s);
            }
        } else {
#pragma unroll
            for (int r = 0; r < 4; r++) {
                int node = base + w * 16 + sgq * 4 + r;
                if (node < N) {
                    float v = acc[r] + bv;
                    if (RELU) v = fmaxf(v, 0.f);
                    int oc = nt * 16 + hl;
                    out16[(size_t)node * OUTC + oc] = f2b(v);
                    unsigned char pv = f2fp8(v);
                    if (oc < OUTC / 2)
                        out8a[(size_t)node * (OUTC / 2) + oc] = pv;
                    else
                        out8b[(size_t)node * (OUTC / 2) + oc - OUTC / 2] = pv;
                }
            }
        }
    }
}

// ---------------- finalize (+cnt via per-block binary search) ----------------
__global__ __launch_bounds__(128) void finalize_kernel(const float* __restrict__ pooled,
                                                       const int* __restrict__ batch,
                                                       float* __restrict__ out, int N) {
    __shared__ float cinv;
    const int g = blockIdx.x;
    if (threadIdx.x == 0) {
        int lo = 0, hi = N;
        while (lo < hi) { int m = (lo + hi) >> 1; if (batch[m] < g) lo = m + 1; else hi = m; }
        int a = lo;
        lo = 0; hi = N;
        while (lo < hi) { int m = (lo + hi) >> 1; if (batch[m] < g + 1) lo = m + 1; else hi = m; }
        cinv = 1.0f / fmaxf((float)(lo - a), 1.0f);
    }
    __syncthreads();
    out[g * OUT_CH + threadIdx.x] = pooled[g * OUT_CH + threadIdx.x] * cinv;
}

extern "C" void kernel_launch(void* const* d_in, const int* in_sizes, int n_in,
                              void* d_out, int out_size, void* d_ws, size_t ws_size,
                              hipStream_t stream) {
    const float* x    = (const float*)d_in[0];
    const int*   ei   = (const int*)d_in[1];
    const int*   bat  = (const int*)d_in[2];
    const float* Wl1  = (const float*)d_in[3];
    const float* Wr1  = (const float*)d_in[4];
    const float* b1   = (const float*)d_in[5];
    const float* Wl2  = (const float*)d_in[6];
    const float* Wr2  = (const float*)d_in[7];
    const float* b2   = (const float*)d_in[8];
    float* out = (float*)d_out;

    const int N = in_sizes[0] / IN_CH;        // 100000
    const int E = in_sizes[1] / 2;            // 1000000
    const int* srcp = ei;
    const int* dstp = ei + E;
    const int NBUCK = (N + BROWS - 1) >> NBUCK_SHIFT;   // 196

    // workspace layout (256B aligned); total ~50 MB
    char* ws = (char*)d_ws;
    size_t off = 0;
    auto alloc = [&](size_t bytes) { size_t p = off; off += (bytes + 255) & ~255ull; return p; };
    size_t pooled_off = alloc((size_t)N_GRAPHS * OUT_CH * 4); // zeroed
    size_t zero_end   = off;
    size_t bcur_off   = alloc(256 * 4);
    size_t xb16_off   = alloc((size_t)N * 64 * 2);            // x bf16 (self)
    size_t xb8a_off   = alloc((size_t)N * 32);                // x fp8 plane a
    size_t xb8b_off   = alloc((size_t)N * 32);                // x fp8 plane b
    size_t hb16_off   = alloc((size_t)N * 64 * 2);            // h bf16 (self)
    size_t hb8a_off   = alloc((size_t)N * 32);                // h fp8 plane a
    size_t hb8b_off   = alloc((size_t)N * 32);                // h fp8 plane b
    size_t rowptr_off = alloc(((size_t)NBUCK * BROWS + 1) * 4);
    size_t staged_off = alloc((size_t)NBUCK * CAPB * 4);      // padded staged
    size_t csr_off    = alloc((size_t)NBUCK * CAPB * 4);      // padded CSR
    size_t wc1_off    = alloc((size_t)64 * 128 * 2);
    size_t wc2_off    = alloc((size_t)128 * 128 * 2);
    (void)ws_size;

    float*          pooled = (float*)(ws + pooled_off);
    int*            bcur   = (int*)(ws + bcur_off);
    unsigned short* xb16   = (unsigned short*)(ws + xb16_off);
    unsigned char*  xb8a   = (unsigned char*)(ws + xb8a_off);
    unsigned char*  xb8b   = (unsigned char*)(ws + xb8b_off);
    unsigned short* hb16   = (unsigned short*)(ws + hb16_off);
    unsigned char*  hb8a   = (unsigned char*)(ws + hb8a_off);
    unsigned char*  hb8b   = (unsigned char*)(ws + hb8b_off);
    int*            rowptr = (int*)(ws + rowptr_off);
    int*            staged = (int*)(ws + staged_off);
    int*            csr    = (int*)(ws + csr_off);
    unsigned short* wc1    = (unsigned short*)(ws + wc1_off);
    unsigned short* wc2    = (unsigned short*)(ws + wc2_off);

    (void)hipMemsetAsync(ws, 0, zero_end, stream);            // pooled only

    const int n4 = N * 64 / 4;
    const int prep_total = n4 + 64 * 128 + 128 * 128;
    const int prep_blocks = (prep_total + 255) / 256;
    const int nch = (E + 4095) / 4096;

    // prep (+bcur init) -> binA -> binB
    prep_kernel<<<prep_blocks + 1, 256, 0, stream>>>(
        x, Wl1, Wr1, Wl2, Wr2, xb16, xb8a, xb8b, wc1, wc2, bcur, n4, NBUCK);
    binA_kernel<<<nch, 256, 0, stream>>>(srcp, dstp, bcur, staged, E);
    binB_kernel<<<NBUCK, 256, 0, stream>>>(staged, bcur, csr, rowptr);

    // fused convs
    const int nblk = (N + 63) / 64;
    sage_kernel<64, true, false><<<nblk, 256, 0, stream>>>(
        xb8a, xb8b, xb16, csr, rowptr, bcur, wc1, b1,
        hb16, hb8a, hb8b, nullptr, nullptr, N);
    sage_kernel<128, false, true><<<nblk, 256, 0, stream>>>(
        hb8a, hb8b, hb16, csr, rowptr, bcur, wc2, b2,
        nullptr, nullptr, nullptr, bat, pooled, N);

    // finalize (+cnt)
    finalize_kernel<<<N_GRAPHS, 128, 0, stream>>>(pooled, bat, out, N);
}

// Round 18
// 127.530 us; speedup vs baseline: 1.0893x; 1.0893x over previous
//
#include <hip/hip_runtime.h>

// GraphSAGE 2-layer + global mean pool.
// N=100000 nodes, E=1e6 edges, 64 -> 64 (relu) -> 128 channels, 128 graphs.
// Pipeline: {prep + bcur-init fused} -> binA (fixed-capacity bucket staging)
// -> binB (per-bucket row sort -> padded CSR + rowptr) -> sage conv1/conv2
// (4-lane-slot 1-row gather over FP8 table + MFMA; conv2 fuses register
// mean-pool) -> finalize(+cnt).
//
// ROOFLINE NOTE (rounds 7-17): the edge gather is bound by the random
// line-transaction rate (~1M 64B-line fetches/conv @ ~22G lines/s). Shown
// insensitive to occupancy (x1.8), pipeline depth (2/4/8), per-wave MLP (x2),
// bytes/line (128->64->32B), and L2 residency (quartile phasing, split
// planes). fp8 single-table (1 row = 1 line) is the optimum found.

#define IN_CH       64
#define OUT_CH      128
#define N_GRAPHS    128
#define NBUCK_SHIFT 9
#define BROWS       512      // rows per coarse bucket
#define CAPB        8192     // fixed staged/csr capacity per bucket (mean 5120)

typedef __attribute__((ext_vector_type(8))) short bf16x8;   // 8 bf16 = 4 VGPR
typedef __attribute__((ext_vector_type(4))) float f32x4;
typedef __attribute__((ext_vector_type(2))) float f32x2;

#if defined(__has_builtin)
#  if __has_builtin(__builtin_amdgcn_cvt_pk_f32_fp8) && __has_builtin(__builtin_amdgcn_cvt_pk_fp8_f32)
#    define HAS_HW_FP8 1
#  endif
#endif
#ifndef HAS_HW_FP8
#  define HAS_HW_FP8 0
#endif

__device__ __forceinline__ unsigned short f2b(float f) {    // RNE float->bf16
    unsigned int u = __float_as_uint(f);
    return (unsigned short)((u + 0x7FFFu + ((u >> 16) & 1u)) >> 16);
}

#if !HAS_HW_FP8
__device__ __forceinline__ unsigned fp8_enc(float f) {      // e4m3fn RNE
    unsigned u = __float_as_uint(f);
    unsigned s = (u >> 24) & 0x80u;
    float a = fabsf(f);
    if (a >= 448.f) return s | 0x7Eu;
    if (a < 0.015625f) { int m = (int)rintf(a * 512.f); return s | (unsigned)m; }
    unsigned au = __float_as_uint(a);
    au += 0x7FFFFu + ((au >> 20) & 1u);
    if ((au >> 23) > 135u) return s | 0x7Eu;
    return s | (((au >> 20) & 0x7FFu) - (120u << 3));
}
__device__ __forceinline__ float fp8_dec1(unsigned b) {
    unsigned s = (b & 0x80u) << 24, m = b & 0x7Fu;
    if (m >= 0x08u) return __uint_as_float(s | ((m << 20) + (120u << 23)));
    float v = (float)m * 0.001953125f;
    return __uint_as_float(__float_as_uint(v) | s);
}
#endif

template <bool HI>
__device__ __forceinline__ f32x2 fp8x2_dec(unsigned u) {
#if HAS_HW_FP8
    return __builtin_amdgcn_cvt_pk_f32_fp8((int)u, HI);     // HI immediate
#else
    f32x2 r;
    unsigned b0 = HI ? ((u >> 16) & 0xFFu) : (u & 0xFFu);
    unsigned b1 = HI ? (u >> 24) : ((u >> 8) & 0xFFu);
    r.x = fp8_dec1(b0); r.y = fp8_dec1(b1);
    return r;
#endif
}

__device__ __forceinline__ unsigned fp8x4_enc(float a, float b, float c, float d) {
#if HAS_HW_FP8
    int p = __builtin_amdgcn_cvt_pk_fp8_f32(a, b, 0, false);
    p = __builtin_amdgcn_cvt_pk_fp8_f32(c, d, p, true);
    return (unsigned)p;
#else
    return fp8_enc(a) | (fp8_enc(b) << 8) | (fp8_enc(c) << 16) | (fp8_enc(d) << 24);
#endif
}

__device__ __forceinline__ unsigned char f2fp8(float v) {
#if HAS_HW_FP8
    return (unsigned char)(__builtin_amdgcn_cvt_pk_fp8_f32(v, v, 0, false) & 0xFF);
#else
    return (unsigned char)fp8_enc(v);
#endif
}

// pack 8 consecutive f32 (LDS) * inv -> bf16x8
__device__ __forceinline__ bf16x8 pack8(const float* p, float inv) {
    union { bf16x8 v; unsigned int u[4]; } r;
#pragma unroll
    for (int i = 0; i < 4; i++) {
        unsigned int lo = f2b(p[2 * i] * inv);
        unsigned int hi = f2b(p[2 * i + 1] * inv);
        r.u[i] = (hi << 16) | lo;
    }
    return r.v;
}

// ---------------- prep (+ bcur init in last block) ----------------
__global__ __launch_bounds__(256) void prep_kernel(const float* __restrict__ x,
                                                   const float* __restrict__ Wl1,
                                                   const float* __restrict__ Wr1,
                                                   const float* __restrict__ Wl2,
                                                   const float* __restrict__ Wr2,
                                                   unsigned short* __restrict__ xb16,
                                                   unsigned char* __restrict__ xb8,
                                                   unsigned short* __restrict__ wc1,
                                                   unsigned short* __restrict__ wc2,
                                                   int* __restrict__ bcur,
                                                   int n4, int nbuck) {
    if ((int)blockIdx.x == (int)gridDim.x - 1) {
        if ((int)threadIdx.x < nbuck) bcur[threadIdx.x] = threadIdx.x * CAPB;
        return;
    }
    int i = blockIdx.x * 256 + threadIdx.x;
    if (i < n4) {
        float4 v = ((const float4*)x)[i];
        ushort4 o;
        o.x = f2b(v.x); o.y = f2b(v.y); o.z = f2b(v.z); o.w = f2b(v.w);
        ((ushort4*)xb16)[i] = o;
        ((unsigned*)xb8)[i] = fp8x4_enc(v.x, v.y, v.z, v.w);
    } else {
        int j = i - n4;
        if (j < 64 * 128) {
            int oc = j >> 7, k = j & 127;
            float v = (k < 64) ? Wl1[oc * 64 + k] : Wr1[oc * 64 + k - 64];
            wc1[j] = f2b(v);
        } else if (j < 64 * 128 + 128 * 128) {
            int jj = j - 64 * 128;
            int oc = jj >> 7, k = jj & 127;
            float v = (k < 64) ? Wl2[oc * 64 + k] : Wr2[oc * 64 + k - 64];
            wc2[jj] = f2b(v);
        }
    }
}

// ---------------- binA: bin edges into fixed-capacity buckets ----------------
// packed staged value: (local_row<<17) | src   (src < 2^17, local_row < 512)
__global__ __launch_bounds__(256) void binA_kernel(const int* __restrict__ src,
                                                   const int* __restrict__ dst,
                                                   int* __restrict__ bcur,
                                                   int* __restrict__ staged, int E) {
    constexpr int CH = 4096;
    __shared__ int cnt[256];
    __shared__ int cur[256];
    __shared__ int gbase[256];
    __shared__ int lstart[256];
    __shared__ int tmp[256];
    __shared__ int sortedv[CH];
    __shared__ unsigned char sortedb[CH];

    const int tid = threadIdx.x;
    const int e0 = blockIdx.x * CH;
    const int n = min(CH, E - e0);

    cnt[tid] = 0;
    __syncthreads();
    for (int i = tid; i < n; i += 256)
        atomicAdd(&cnt[dst[e0 + i] >> NBUCK_SHIFT], 1);
    __syncthreads();
    int v = cnt[tid];
    int inc = v;
    tmp[tid] = inc;
    __syncthreads();
    for (int o = 1; o < 256; o <<= 1) {
        int t = (tid >= o) ? tmp[tid - o] : 0;
        __syncthreads();
        inc += t;
        tmp[tid] = inc;
        __syncthreads();
    }
    lstart[tid] = inc - v;
    cur[tid] = inc - v;
    if (v > 0) gbase[tid] = atomicAdd(&bcur[tid], v);
    __syncthreads();
    for (int i = tid; i < n; i += 256) {
        int d = dst[e0 + i], s = src[e0 + i];
        int b = d >> NBUCK_SHIFT;
        int p = atomicAdd(&cur[b], 1);
        sortedv[p] = ((d & (BROWS - 1)) << 17) | s;
        sortedb[p] = (unsigned char)b;
    }
    __syncthreads();
    for (int i = tid; i < n; i += 256) {
        int b = sortedb[i];
        staged[gbase[b] + (i - lstart[b])] = sortedv[i];
    }
}

// ---------------- binB: per-bucket row sort -> padded CSR + rowptr ----------------
// rowptr in PADDED coordinates: rowptr[r] = b*CAPB + prefix; empty/overhang
// rows get prefix = n (monotone). Bucket end is bcur[b] (= b*CAPB + n).
__global__ __launch_bounds__(256) void binB_kernel(const int* __restrict__ staged,
                                                   const int* __restrict__ bcur,
                                                   int* __restrict__ csr,
                                                   int* __restrict__ rowptr) {
    __shared__ int cnt[BROWS];
    __shared__ int cur[BROWS];
    __shared__ int tmp[BROWS];
    __shared__ int sorted[CAPB];

    const int tid = threadIdx.x;
    const int b = blockIdx.x;
    const int r0 = b * BROWS;
    const int base = b * CAPB;
    const int n = bcur[b] - base;

    for (int k = tid; k < BROWS; k += 256) cnt[k] = 0;
    __syncthreads();
    for (int i = tid; i < n; i += 256)
        atomicAdd(&cnt[staged[base + i] >> 17], 1);
    __syncthreads();
    tmp[tid] = cnt[tid];
    tmp[tid + 256] = cnt[tid + 256];
    __syncthreads();
    for (int o = 1; o < BROWS; o <<= 1) {
        int t0 = (tid >= o) ? tmp[tid - o] : 0;
        int t1 = (tid + 256 >= o) ? tmp[tid + 256 - o] : 0;
        __syncthreads();
        tmp[tid] += t0;
        tmp[tid + 256] += t1;
        __syncthreads();
    }
    cur[tid] = tmp[tid] - cnt[tid];
    cur[tid + 256] = tmp[tid + 256] - cnt[tid + 256];
    rowptr[r0 + tid] = base + cur[tid];               // all rows, incl. empty
    rowptr[r0 + tid + 256] = base + cur[tid + 256];
    __syncthreads();
    for (int i = tid; i < n; i += 256) {
        int p = staged[base + i];
        int pos = atomicAdd(&cur[p >> 17], 1);
        if (pos < CAPB) sorted[pos] = p & 0x1FFFF;
    }
    __syncthreads();
    for (int i = tid; i < n; i += 256)
        csr[base + i] = sorted[min(i, CAPB - 1)];
}

// ---------------- fused SAGE conv ----------------
// Block = 64 dst nodes, 8 blocks/CU. 64 slots (4 waves x 16, 4 lanes each);
// slot owns ONE row; a lane loads uint4 = 16 fp8 feats so the slot's 4 lanes
// fetch the whole 64B row in one instruction; 4-deep pipeline. Out-of-range
// prefetches use row 0 (hot line). rp[64] at a bucket boundary comes from
// bcur[b]. MFMA: K=128 (k<64 neighbor-mean LDS tile, k>=64 bf16 self), B from
// global. POOL: register shfl-reduce mean-pool epilogue.
template <int OUTC, bool RELU, bool POOL>
__global__ __launch_bounds__(256, 8) void sage_kernel(
    const unsigned char* __restrict__ f8,       // [N,64] fp8 e4m3 (gather)
    const unsigned short* __restrict__ f16,     // [N,64] bf16 (self)
    const int* __restrict__ csr,                // padded CSR (src only)
    const int* __restrict__ rowptr,             // padded coords
    const int* __restrict__ bcur,               // bucket ends
    const unsigned short* __restrict__ wc,      // [OUTC,128] bf16
    const float* __restrict__ bias,             // [OUTC] f32
    unsigned short* __restrict__ out16,         // bf16 [N,OUTC] (POOL=false)
    unsigned char* __restrict__ out8,           // fp8  [N,OUTC] (POOL=false)
    const int* __restrict__ batch,              // [N] (POOL)
    float* __restrict__ pooled,                 // [G,OUTC] f32 (POOL)
    int N) {
    constexpr int LDA = 68;
    __shared__ float agg[64 * LDA];             // 17.4 KB
    __shared__ int rp[65];
    __shared__ int bt[64];

    const int tid = threadIdx.x, lane = tid & 63, w = tid >> 6;
    const int base = blockIdx.x * 64;

    for (int i = tid; i < 64 * LDA; i += 256) agg[i] = 0.f;
    if (tid < 64) rp[tid] = rowptr[base + tid];
    if (tid == 64) {
        int idx = base + 64;
        rp[64] = ((idx & (BROWS - 1)) == 0) ? bcur[(idx >> NBUCK_SHIFT) - 1]
                                            : rowptr[idx];
    }
    if (POOL && tid < 64) bt[tid] = batch[min(base + tid, N - 1)];
    __syncthreads();

    // ---- gather: 4-lane slot owns one row; 4-deep pipeline ----
    {
        const int sl = (w << 4) | (lane >> 2); // slot 0..63 = local row
        const int fl = lane & 3;               // feature 16-group
        int e0 = rp[sl];
        const int end = rp[sl + 1];
        if (e0 < end) {
            const uint4* f8v = reinterpret_cast<const uint4*>(f8);  // row = 4 x uint4
            float a0 = 0.f, a1 = 0.f, a2 = 0.f, a3 = 0.f;
            float a4 = 0.f, a5 = 0.f, a6 = 0.f, a7 = 0.f;
            float a8 = 0.f, a9 = 0.f, aA = 0.f, aB = 0.f;
            float aC = 0.f, aD = 0.f, aE = 0.f, aF = 0.f;
#define CIDX(EI) (((EI) < end) ? csr[EI] : 0)
            int c4_ = CIDX(e0 + 4), c5_ = CIDX(e0 + 5);
            int c6_ = CIDX(e0 + 6), c7_ = CIDX(e0 + 7);
            uint4 v0 = f8v[(size_t)CIDX(e0 + 0) * 4 + fl];
            uint4 v1 = f8v[(size_t)CIDX(e0 + 1) * 4 + fl];
            uint4 v2 = f8v[(size_t)CIDX(e0 + 2) * 4 + fl];
            uint4 v3 = f8v[(size_t)CIDX(e0 + 3) * 4 + fl];

#define PROC(VV, EI)                                                             \
    do {                                                                         \
        if ((EI) < end) {                                                        \
            f32x2 d;                                                             \
            d = fp8x2_dec<false>(VV.x); a0 += d.x; a1 += d.y;                    \
            d = fp8x2_dec<true >(VV.x); a2 += d.x; a3 += d.y;                    \
            d = fp8x2_dec<false>(VV.y); a4 += d.x; a5 += d.y;                    \
            d = fp8x2_dec<true >(VV.y); a6 += d.x; a7 += d.y;                    \
            d = fp8x2_dec<false>(VV.z); a8 += d.x; a9 += d.y;                    \
            d = fp8x2_dec<true >(VV.z); aA += d.x; aB += d.y;                    \
            d = fp8x2_dec<false>(VV.w); aC += d.x; aD += d.y;                    \
            d = fp8x2_dec<true >(VV.w); aE += d.x; aF += d.y;                    \
        }                                                                        \
    } while (0)

            for (int e = e0; e < end; e += 4) {
                PROC(v0, e + 0);
                v0 = f8v[(size_t)c4_ * 4 + fl];
                PROC(v1, e + 1);
                v1 = f8v[(size_t)c5_ * 4 + fl];
                PROC(v2, e + 2);
                v2 = f8v[(size_t)c6_ * 4 + fl];
                PROC(v3, e + 3);
                v3 = f8v[(size_t)c7_ * 4 + fl];
                c4_ = CIDX(e + 8);
                c5_ = CIDX(e + 9);
                c6_ = CIDX(e + 10);
                c7_ = CIDX(e + 11);
            }
            float* dp = &agg[sl * LDA + fl * 16];
            *reinterpret_cast<float4*>(dp + 0)  = make_float4(a0, a1, a2, a3);
            *reinterpret_cast<float4*>(dp + 4)  = make_float4(a4, a5, a6, a7);
            *reinterpret_cast<float4*>(dp + 8)  = make_float4(a8, a9, aA, aB);
            *reinterpret_cast<float4*>(dp + 12) = make_float4(aC, aD, aE, aF);
#undef PROC
#undef CIDX
        }
    }
    __syncthreads();

    // ---- MFMA phase ----
    const int hl = lane & 15, sgq = lane >> 4;
    const int row = w * 16 + hl;
    float inv = 1.0f / fmaxf((float)(rp[row + 1] - rp[row]), 1.0f);
    const float* ar = &agg[row * LDA];
    bf16x8 a[4];
    a[0] = pack8(ar + sgq * 8, inv);
    a[1] = pack8(ar + 32 + sgq * 8, inv);
    int nclamp = min(base + row, N - 1);
    const unsigned short* srow = &f16[(size_t)nclamp * 64];
    a[2] = *reinterpret_cast<const bf16x8*>(&srow[sgq * 8]);
    a[3] = *reinterpret_cast<const bf16x8*>(&srow[32 + sgq * 8]);

    int gw0 = 0, gw1 = -1;
    int myg[4];
    bool mval[4];
    if (POOL) {
        gw0 = bt[w * 16];
        gw1 = bt[w * 16 + 15];
#pragma unroll
        for (int r = 0; r < 4; r++) {
            int lrow = w * 16 + sgq * 4 + r;
            mval[r] = (base + lrow) < N;
            myg[r] = bt[lrow];
        }
    }

    constexpr int NT = OUTC / 16;
#pragma unroll
    for (int nt = 0; nt < NT; nt++) {
        f32x4 acc = {0.f, 0.f, 0.f, 0.f};
#pragma unroll
        for (int ks = 0; ks < 4; ks++) {
            bf16x8 b = *reinterpret_cast<const bf16x8*>(
                &wc[(nt * 16 + hl) * 128 + ks * 32 + sgq * 8]);
            acc = __builtin_amdgcn_mfma_f32_16x16x32_bf16(a[ks], b, acc, 0, 0, 0);
        }
        float bv = bias[nt * 16 + hl];
        if (POOL) {
            for (int g = gw0; g <= gw1; g++) {
                float s = 0.f;
#pragma unroll
                for (int r = 0; r < 4; r++) {
                    float v = acc[r] + bv;
                    if (RELU) v = fmaxf(v, 0.f);
                    s += (mval[r] && myg[r] == g) ? v : 0.f;
                }
                s += __shfl_xor(s, 16);
                s += __shfl_xor(s, 32);
                if (lane < 16) atomicAdd(&pooled[g * OUTC + nt * 16 + lane], s);
            }
        } else {
#pragma unroll
            for (int r = 0; r < 4; r++) {
                int node = base + w * 16 + sgq * 4 + r;
                if (node < N) {
                    float v = acc[r] + bv;
                    if (RELU) v = fmaxf(v, 0.f);
                    int oc = nt * 16 + hl;
                    out16[(size_t)node * OUTC + oc] = f2b(v);
                    out8[(size_t)node * OUTC + oc] = f2fp8(v);
                }
            }
        }
    }
}

// ---------------- finalize (+cnt via per-block binary search) ----------------
__global__ __launch_bounds__(128) void finalize_kernel(const float* __restrict__ pooled,
                                                       const int* __restrict__ batch,
                                                       float* __restrict__ out, int N) {
    __shared__ float cinv;
    const int g = blockIdx.x;
    if (threadIdx.x == 0) {
        int lo = 0, hi = N;
        while (lo < hi) { int m = (lo + hi) >> 1; if (batch[m] < g) lo = m + 1; else hi = m; }
        int a = lo;
        lo = 0; hi = N;
        while (lo < hi) { int m = (lo + hi) >> 1; if (batch[m] < g + 1) lo = m + 1; else hi = m; }
        cinv = 1.0f / fmaxf((float)(lo - a), 1.0f);
    }
    __syncthreads();
    out[g * OUT_CH + threadIdx.x] = pooled[g * OUT_CH + threadIdx.x] * cinv;
}

extern "C" void kernel_launch(void* const* d_in, const int* in_sizes, int n_in,
                              void* d_out, int out_size, void* d_ws, size_t ws_size,
                              hipStream_t stream) {
    const float* x    = (const float*)d_in[0];
    const int*   ei   = (const int*)d_in[1];
    const int*   bat  = (const int*)d_in[2];
    const float* Wl1  = (const float*)d_in[3];
    const float* Wr1  = (const float*)d_in[4];
    const float* b1   = (const float*)d_in[5];
    const float* Wl2  = (const float*)d_in[6];
    const float* Wr2  = (const float*)d_in[7];
    const float* b2   = (const float*)d_in[8];
    float* out = (float*)d_out;

    const int N = in_sizes[0] / IN_CH;        // 100000
    const int E = in_sizes[1] / 2;            // 1000000
    const int* srcp = ei;
    const int* dstp = ei + E;
    const int NBUCK = (N + BROWS - 1) >> NBUCK_SHIFT;   // 196

    // workspace layout (256B aligned); total ~50 MB
    char* ws = (char*)d_ws;
    size_t off = 0;
    auto alloc = [&](size_t bytes) { size_t p = off; off += (bytes + 255) & ~255ull; return p; };
    size_t pooled_off = alloc((size_t)N_GRAPHS * OUT_CH * 4); // zeroed
    size_t zero_end   = off;
    size_t bcur_off   = alloc(256 * 4);
    size_t xb16_off   = alloc((size_t)N * 64 * 2);            // x bf16 (self)
    size_t xb8_off    = alloc((size_t)N * 64);                // x fp8 (gather)
    size_t hb16_off   = alloc((size_t)N * 64 * 2);            // h bf16 (self)
    size_t hb8_off    = alloc((size_t)N * 64);                // h fp8 (gather)
    size_t rowptr_off = alloc(((size_t)NBUCK * BROWS + 1) * 4);
    size_t staged_off = alloc((size_t)NBUCK * CAPB * 4);      // padded staged
    size_t csr_off    = alloc((size_t)NBUCK * CAPB * 4);      // padded CSR
    size_t wc1_off    = alloc((size_t)64 * 128 * 2);
    size_t wc2_off    = alloc((size_t)128 * 128 * 2);
    (void)ws_size;

    float*          pooled = (float*)(ws + pooled_off);
    int*            bcur   = (int*)(ws + bcur_off);
    unsigned short* xb16   = (unsigned short*)(ws + xb16_off);
    unsigned char*  xb8    = (unsigned char*)(ws + xb8_off);
    unsigned short* hb16   = (unsigned short*)(ws + hb16_off);
    unsigned char*  hb8    = (unsigned char*)(ws + hb8_off);
    int*            rowptr = (int*)(ws + rowptr_off);
    int*            staged = (int*)(ws + staged_off);
    int*            csr    = (int*)(ws + csr_off);
    unsigned short* wc1    = (unsigned short*)(ws + wc1_off);
    unsigned short* wc2    = (unsigned short*)(ws + wc2_off);

    (void)hipMemsetAsync(ws, 0, zero_end, stream);            // pooled only

    const int n4 = N * 64 / 4;
    const int prep_total = n4 + 64 * 128 + 128 * 128;
    const int prep_blocks = (prep_total + 255) / 256;
    const int nch = (E + 4095) / 4096;

    // prep (+bcur init) -> binA -> binB
    prep_kernel<<<prep_blocks + 1, 256, 0, stream>>>(
        x, Wl1, Wr1, Wl2, Wr2, xb16, xb8, wc1, wc2, bcur, n4, NBUCK);
    binA_kernel<<<nch, 256, 0, stream>>>(srcp, dstp, bcur, staged, E);
    binB_kernel<<<NBUCK, 256, 0, stream>>>(staged, bcur, csr, rowptr);

    // fused convs
    const int nblk = (N + 63) / 64;
    sage_kernel<64, true, false><<<nblk, 256, 0, stream>>>(
        xb8, xb16, csr, rowptr, bcur, wc1, b1, hb16, hb8, nullptr, nullptr, N);
    sage_kernel<128, false, true><<<nblk, 256, 0, stream>>>(
        hb8, hb16, csr, rowptr, bcur, wc2, b2, nullptr, nullptr, bat, pooled, N);

    // finalize (+cnt)
    finalize_kernel<<<N_GRAPHS, 128, 0, stream>>>(pooled, bat, out, N);
}